// Round 2
// baseline (462.215 us; speedup 1.0000x reference)
//
#include <hip/hip_runtime.h>

// Problem constants (fixed by reference): B=128, L=256, F=P=4, IN=1024, H=256, C=7
#define NN 32768        // N = B*L
#define INF 1024
#define HF 256

typedef __bf16 bf16x8 __attribute__((ext_vector_type(8)));
typedef float f32x4 __attribute__((ext_vector_type(4)));

__device__ __forceinline__ float bf2f(unsigned short u) {
  union { unsigned int i; float f; } v; v.i = ((unsigned int)u) << 16; return v.f;
}
__device__ __forceinline__ unsigned short f2bf(float f) {
  union { float f; unsigned int i; } v; v.f = f;
  unsigned int x = v.i;
  return (unsigned short)((x + 0x7fffu + ((x >> 16) & 1u)) >> 16);  // RNE
}

// async global->LDS, 16B per lane; dest = lds base (wave-uniform) + lane*16
__device__ __forceinline__ void ld_lds16(const unsigned short* g, unsigned short* l) {
  __builtin_amdgcn_global_load_lds(
      (__attribute__((address_space(1))) const unsigned int*)g,
      (__attribute__((address_space(3))) unsigned int*)l, 16, 0, 0);
}

// ---- prep: x fp32->bf16 (blocks [0,32768)), weight repack (blocks [32768,37376))
// WbigT[n][k] (1024x1024) = [W0|W1|Wroot|Wskip]^T ; WsmT[n][k] (256x512) = [Wgrt;Wrel]^T
__global__ void diagcn_prep(const float* __restrict__ x, const float* __restrict__ Wrgcn,
                            const float* __restrict__ Wroot, const float* __restrict__ Wskip,
                            const float* __restrict__ Wgrt, const float* __restrict__ Wrel,
                            unsigned short* __restrict__ Xbf, unsigned short* __restrict__ WbigT,
                            unsigned short* __restrict__ WsmT) {
  int bid = blockIdx.x;
  if (bid < 32768) {
    int idx = bid * 256 + threadIdx.x;   // float4 index into x
    float4 v = ((const float4*)x)[idx];
    ushort4 u; u.x = f2bf(v.x); u.y = f2bf(v.y); u.z = f2bf(v.z); u.w = f2bf(v.w);
    ((ushort4*)Xbf)[idx] = u;
  } else {
    int idx = (bid - 32768) * 256 + threadIdx.x;
    if (idx < 1024 * 1024) {
      int n = idx >> 10, k = idx & 1023;
      float v;
      if (n < 256)      v = Wrgcn[k * 256 + n];
      else if (n < 512) v = Wrgcn[262144 + k * 256 + (n - 256)];
      else if (n < 768) v = Wroot[k * 256 + (n - 512)];
      else              v = Wskip[k * 256 + (n - 768)];
      WbigT[idx] = f2bf(v);
    } else {
      int i2 = idx - 1024 * 1024;             // < 131072
      int n = i2 >> 9, k = i2 & 511;
      float v = (k < 256) ? Wgrt[k * 256 + n] : Wrel[(k - 256) * 256 + n];
      WsmT[i2] = f2bf(v);
    }
  }
}

// ---- bf16 GEMM: C[M x Nt] = A[M x K] * BT[Nt x K]^T, 128x128 tile, BK=64.
// XCD-aware swizzle: xcd = b&7 owns m-tiles [xcd*32, xcd*32+32); its NT n-tiles for one
// m-tile are consecutive (stride-8) in dispatch order -> A panel L2-resident per XCD.
// EPI=0: store bf16 to Y (ldc=1024). EPI=1: z = acc + brel + bskip + Yskip, fp32 (ldc=256).
template <int EPI, int NT, int L2NT>
__global__ __launch_bounds__(256)
void diagcn_gemm(const unsigned short* __restrict__ A, const unsigned short* __restrict__ BT,
                 void* __restrict__ Cout, const unsigned short* __restrict__ Yfull,
                 const float* __restrict__ brel, const float* __restrict__ bskip, int K) {
  __shared__ unsigned short As[128 * 64];
  __shared__ unsigned short Bs[128 * 64];
  const int tid = threadIdx.x;
  const int w = tid >> 6, lane = tid & 63;
  const int wm = w >> 1, wn = w & 1;
  const int quad = lane >> 4, l15 = lane & 15;
  const int b = blockIdx.x;
  const int m0 = (((b & 7) << 5) + (b >> (3 + L2NT))) << 7;
  const int n0 = ((b >> 3) & (NT - 1)) << 7;
  const int rowg = lane >> 3;                 // 0..7 within 8-row group
  const int kbsw = (lane & 7) ^ rowg;         // XOR-swizzled source k-block

  f32x4 acc[4][4] = {};

  const unsigned short* Abase = A + (size_t)m0 * K + kbsw * 8;
  const unsigned short* Bbase = BT + (size_t)n0 * K + kbsw * 8;

  for (int k0 = 0; k0 < K; k0 += 64) {
#pragma unroll
    for (int t = 0; t < 4; ++t) {
      int grp = w * 4 + t;                    // 16 groups of 8 rows
      int rl = grp * 8 + rowg;
      ld_lds16(Abase + (size_t)rl * K + k0, &As[grp * 512]);
      ld_lds16(Bbase + (size_t)rl * K + k0, &Bs[grp * 512]);
    }
    __syncthreads();
#pragma unroll
    for (int ks = 0; ks < 2; ++ks) {
      bf16x8 av[4], bv[4];
      int kb = ks * 4 + quad;
#pragma unroll
      for (int i = 0; i < 4; ++i) {
        int ra = wm * 64 + i * 16 + l15;
        int rb = wn * 64 + i * 16 + l15;
        av[i] = *(const bf16x8*)&As[ra * 64 + ((kb ^ (ra & 7)) << 3)];
        bv[i] = *(const bf16x8*)&Bs[rb * 64 + ((kb ^ (rb & 7)) << 3)];
      }
#pragma unroll
      for (int i = 0; i < 4; ++i)
#pragma unroll
        for (int j = 0; j < 4; ++j)
          acc[i][j] = __builtin_amdgcn_mfma_f32_16x16x32_bf16(av[i], bv[j], acc[i][j], 0, 0, 0);
    }
    __syncthreads();
  }

  if (EPI == 0) {
    unsigned short* Y = (unsigned short*)Cout;
#pragma unroll
    for (int i = 0; i < 4; ++i)
#pragma unroll
      for (int j = 0; j < 4; ++j) {
        int row = m0 + wm * 64 + i * 16 + quad * 4;
        int col = n0 + wn * 64 + j * 16 + l15;
#pragma unroll
        for (int r = 0; r < 4; ++r)
          Y[(size_t)(row + r) * 1024 + col] = f2bf(acc[i][j][r]);
      }
  } else {
    float* Z = (float*)Cout;
#pragma unroll
    for (int i = 0; i < 4; ++i)
#pragma unroll
      for (int j = 0; j < 4; ++j) {
        int row = m0 + wm * 64 + i * 16 + quad * 4;
        int col = n0 + wn * 64 + j * 16 + l15;
#pragma unroll
        for (int r = 0; r < 4; ++r) {
          float v = acc[i][j][r] + brel[col] + bskip[col] +
                    bf2f(Yfull[(size_t)(row + r) * 1024 + 768 + col]);
          Z[(size_t)(row + r) * 256 + col] = v;
        }
      }
  }
}

// ---- fused RGCN-aggregate + GraphConv neighbor sum.
// One block per 64-node dialog chunk. Phase 1: compute h (bf16) for the chunk
// +4-node halo into LDS, write owned h to A2[:,0:256]. Phase 2: 9-window sum of
// LDS h -> A2[:,256:512]. Eliminates the fp32 h HBM round-trip.
__global__ __launch_bounds__(256)
void diagcn_hneigh(const unsigned short* __restrict__ Y, const int* __restrict__ spk,
                   const float* __restrict__ brgcn, unsigned short* __restrict__ A2) {
  __shared__ unsigned short hl[72 * 256];
  const int nbase = blockIdx.x * 64;       // first owned node
  const int p0 = nbase & 255;              // position within dialog (0/64/128/192)
  const int dbase = nbase - p0;            // dialog start node
  const int wv = threadIdx.x >> 6, lane = threadIdx.x & 63;
  const int c0 = lane << 2;
  const float4 bv = *(const float4*)&brgcn[c0];

  for (int t = wv; t < 72; t += 4) {       // h for p in [p0-4, p0+68) clipped
    int p = p0 - 4 + t;
    if (p < 0 || p > 255) continue;
    int node = dbase + p;
    int lo = p - 4; if (lo < 0) lo = 0;
    int hi = p + 4; if (hi > 255) hi = 255;
    int si = spk[node];
    float a0x = 0, a0y = 0, a0z = 0, a0w = 0;
    float a1x = 0, a1y = 0, a1z = 0, a1w = 0;
    int n0 = 0, n1 = 0;
    for (int j = lo; j <= hi; ++j) {
      int nj = dbase + j;
      int sj = spk[nj];
      if (si & sj) {  // rel 1
        ushort4 v = *(const ushort4*)&Y[(size_t)nj * 1024 + 256 + c0];
        a1x += bf2f(v.x); a1y += bf2f(v.y); a1z += bf2f(v.z); a1w += bf2f(v.w);
        n1++;
      } else {        // rel 0
        ushort4 v = *(const ushort4*)&Y[(size_t)nj * 1024 + c0];
        a0x += bf2f(v.x); a0y += bf2f(v.y); a0z += bf2f(v.z); a0w += bf2f(v.w);
        n0++;
      }
    }
    ushort4 vr = *(const ushort4*)&Y[(size_t)node * 1024 + 512 + c0];
    float i0 = 1.0f / (float)(n0 > 1 ? n0 : 1);
    float i1 = 1.0f / (float)(n1 > 1 ? n1 : 1);
    ushort4 u;
    u.x = f2bf(bf2f(vr.x) + bv.x + a0x * i0 + a1x * i1);
    u.y = f2bf(bf2f(vr.y) + bv.y + a0y * i0 + a1y * i1);
    u.z = f2bf(bf2f(vr.z) + bv.z + a0z * i0 + a1z * i1);
    u.w = f2bf(bf2f(vr.w) + bv.w + a0w * i0 + a1w * i1);
    *(ushort4*)&hl[t * 256 + c0] = u;
    if (t >= 4 && t < 68)                  // owned node
      *(ushort4*)&A2[(size_t)node * 512 + c0] = u;
  }
  __syncthreads();
  for (int t = wv; t < 64; t += 4) {       // neighbor sum for owned nodes
    int p = p0 + t;
    int lo = p - 4; if (lo < 0) lo = 0;
    int hi = p + 4; if (hi > 255) hi = 255;
    float sx = 0, sy = 0, sz = 0, sw = 0;
    for (int j = lo; j <= hi; ++j) {
      ushort4 v = *(const ushort4*)&hl[(j - p0 + 4) * 256 + c0];
      sx += bf2f(v.x); sy += bf2f(v.y); sz += bf2f(v.z); sw += bf2f(v.w);
    }
    ushort4 u; u.x = f2bf(sx); u.y = f2bf(sy); u.z = f2bf(sz); u.w = f2bf(sw);
    *(ushort4*)&A2[(size_t)(nbase + t) * 512 + 256 + c0] = u;
  }
}

// ---- classifier + per-node loss: one wave per node
__global__ __launch_bounds__(256)
void diagcn_out(const float* __restrict__ z, const float* __restrict__ Wcls,
                const float* __restrict__ bcls, const int* __restrict__ labels,
                float* __restrict__ out, float* __restrict__ lossp) {
  __shared__ float Wc[256 * 7 + 7];
  for (int i = threadIdx.x; i < 256 * 7 + 7; i += 256)
    Wc[i] = (i < 1792) ? Wcls[i] : bcls[i - 1792];
  __syncthreads();
  int node = blockIdx.x * 4 + (threadIdx.x >> 6);
  int lane = threadIdx.x & 63;
  int c0 = lane << 2;
  float4 zv = *(const float4*)&z[(size_t)node * 256 + c0];
  float zz[4] = {zv.x, zv.y, zv.z, zv.w};
  float pr[7] = {0, 0, 0, 0, 0, 0, 0};
#pragma unroll
  for (int cc = 0; cc < 4; ++cc) {
    const float* wr = &Wc[(c0 + cc) * 7];
#pragma unroll
    for (int k = 0; k < 7; ++k) pr[k] += zz[cc] * wr[k];
  }
#pragma unroll
  for (int o = 32; o > 0; o >>= 1)
#pragma unroll
    for (int k = 0; k < 7; ++k) pr[k] += __shfl_down(pr[k], o, 64);
  if (lane == 0) {
    float o7[7], m = -1e30f;
#pragma unroll
    for (int k = 0; k < 7; ++k) {
      o7[k] = pr[k] + Wc[1792 + k];
      out[(size_t)node * 7 + k] = o7[k];
      m = fmaxf(m, o7[k]);
    }
    float s = 0;
#pragma unroll
    for (int k = 0; k < 7; ++k) s += expf(o7[k] - m);
    int lab = labels[node];
    lossp[node] = m + logf(s) - o7[lab];
  }
}

__global__ void diagcn_lred(const float* __restrict__ lp, float* __restrict__ dst) {
  __shared__ float sm[256];
  float s = 0;
  for (int i = threadIdx.x; i < NN; i += 256) s += lp[i];
  sm[threadIdx.x] = s;
  __syncthreads();
  for (int o = 128; o > 0; o >>= 1) {
    if (threadIdx.x < o) sm[threadIdx.x] += sm[threadIdx.x + o];
    __syncthreads();
  }
  if (threadIdx.x == 0) dst[0] = sm[0] * (1.0f / (float)NN);
}

extern "C" void kernel_launch(void* const* d_in, const int* in_sizes, int n_in,
                              void* d_out, int out_size, void* d_ws, size_t ws_size,
                              hipStream_t stream) {
  const float* x      = (const float*)d_in[0];
  const int* speakers = (const int*)d_in[2];
  const int* labels   = (const int*)d_in[3];
  const float* Wrgcn  = (const float*)d_in[6];
  const float* Wroot  = (const float*)d_in[7];
  const float* brgcn  = (const float*)d_in[8];
  const float* Wrel   = (const float*)d_in[9];
  const float* brel   = (const float*)d_in[10];
  const float* Wgrt   = (const float*)d_in[11];
  const float* Wskip  = (const float*)d_in[12];
  const float* bskip  = (const float*)d_in[13];
  const float* Wcls   = (const float*)d_in[14];
  const float* bcls   = (const float*)d_in[15];
  float* out = (float*)d_out;

  // workspace layout (bytes)
  const size_t OFF_XBF  = 0;                  // 67,108,864  (bf16 X; later reused for z+lossp)
  const size_t OFF_WBIG = 67108864;           //  2,097,152
  const size_t OFF_WSM  = 69206016;           //    262,144
  const size_t OFF_Y    = 69468160;           // 67,108,864  (bf16 [Y0|Y1|Yroot|Yskip])
  const size_t OFF_A2   = 136577024;          // 33,554,432  (bf16 [h|neigh])
  const size_t NEED     = 170131456;
  if (ws_size < NEED) return;  // insufficient scratch — would need a redesign

  char* ws = (char*)d_ws;
  unsigned short* Xbf   = (unsigned short*)(ws + OFF_XBF);
  unsigned short* WbigT = (unsigned short*)(ws + OFF_WBIG);
  unsigned short* WsmT  = (unsigned short*)(ws + OFF_WSM);
  unsigned short* Y     = (unsigned short*)(ws + OFF_Y);
  unsigned short* A2    = (unsigned short*)(ws + OFF_A2);
  float* z              = (float*)(ws + OFF_XBF);               // reuse (Xbf dead after GEMM1)
  float* lossp          = (float*)(ws + OFF_XBF + 33554432);

  diagcn_prep<<<dim3(37376), dim3(256), 0, stream>>>(x, Wrgcn, Wroot, Wskip, Wgrt, Wrel,
                                                     Xbf, WbigT, WsmT);
  // GEMM1: Y[32768 x 1024] = Xbf @ WbigT^T ; 2048 blocks, XCD-swizzled
  diagcn_gemm<0, 8, 3><<<dim3(2048), dim3(256), 0, stream>>>(Xbf, WbigT, (void*)Y,
                                                             nullptr, nullptr, nullptr, 1024);
  diagcn_hneigh<<<dim3(NN / 64), dim3(256), 0, stream>>>(Y, speakers, brgcn, A2);
  // GEMM2: z[32768 x 256] = A2 @ WsmT^T + brel + bskip + Yskip ; 512 blocks, swizzled
  diagcn_gemm<1, 2, 1><<<dim3(512), dim3(256), 0, stream>>>(A2, WsmT, (void*)z,
                                                            Y, brel, bskip, 512);
  diagcn_out<<<dim3(NN / 4), dim3(256), 0, stream>>>(z, Wcls, bcls, labels, out, lossp);
  diagcn_lred<<<dim3(1), dim3(256), 0, stream>>>(lossp, out + (size_t)NN * 7);
}

// Round 3
// 405.131 us; speedup vs baseline: 1.1409x; 1.1409x over previous
//
#include <hip/hip_runtime.h>

// Problem constants (fixed by reference): B=128, L=256, F=P=4, IN=1024, H=256, C=7
#define NN 32768        // N = B*L
#define INF 1024
#define HF 256

typedef __bf16 bf16x8 __attribute__((ext_vector_type(8)));
typedef float f32x4 __attribute__((ext_vector_type(4)));

__device__ __forceinline__ float bf2f(unsigned short u) {
  union { unsigned int i; float f; } v; v.i = ((unsigned int)u) << 16; return v.f;
}
__device__ __forceinline__ unsigned short f2bf(float f) {
  union { float f; unsigned int i; } v; v.f = f;
  unsigned int x = v.i;
  return (unsigned short)((x + 0x7fffu + ((x >> 16) & 1u)) >> 16);  // RNE
}

// async global->LDS, 16B per lane; dest = lds base (wave-uniform) + lane*16
__device__ __forceinline__ void ld_lds16(const unsigned short* g, unsigned short* l) {
  __builtin_amdgcn_global_load_lds(
      (__attribute__((address_space(1))) const unsigned int*)g,
      (__attribute__((address_space(3))) unsigned int*)l, 16, 0, 0);
}

// ---- prep:
//  blocks [0,32768):        x fp32 -> bf16 (coalesced float4 copy)
//  blocks [32768,32768+288): weight repack via 64x64 LDS transpose (coalesced both sides)
// WbigT[n][k] (1024x1024) = [W0|W1|Wroot|Wskip]^T ; WsmT[n][k] (256x512) = [Wgrt;Wrel]^T
__global__ __launch_bounds__(256)
void diagcn_prep(const float* __restrict__ x, const float* __restrict__ Wrgcn,
                 const float* __restrict__ Wroot, const float* __restrict__ Wskip,
                 const float* __restrict__ Wgrt, const float* __restrict__ Wrel,
                 unsigned short* __restrict__ Xbf, unsigned short* __restrict__ WbigT,
                 unsigned short* __restrict__ WsmT) {
  int bid = blockIdx.x;
  if (bid < 32768) {
    int idx = bid * 256 + threadIdx.x;   // float4 index into x
    float4 v = ((const float4*)x)[idx];
    ushort4 u; u.x = f2bf(v.x); u.y = f2bf(v.y); u.z = f2bf(v.z); u.w = f2bf(v.w);
    ((ushort4*)Xbf)[idx] = u;
    return;
  }
  __shared__ float tile[64 * 65];
  int tb = bid - 32768;
  const float* src;          // source matrix [*][256], k-major
  int k0, ncol0;             // source k-row block, source col block
  unsigned short* dst;       // dest row base: dst[(nn)*ldd + k0 + kk]
  int ldd, nrow0;
  if (tb < 256) {            // WbigT tiles: tn 0..15, tk 0..15
    int tn = tb >> 4, tk = tb & 15;
    int mat = tn >> 2;
    src = (mat == 0) ? Wrgcn : (mat == 1) ? (Wrgcn + 262144) : (mat == 2) ? Wroot : Wskip;
    k0 = tk * 64; ncol0 = (tn & 3) * 64;
    dst = WbigT; ldd = 1024; nrow0 = tn * 64;
  } else {                   // WsmT tiles: tn 0..3, tk 0..7
    int t2 = tb - 256;
    int tn = t2 >> 3, tk = t2 & 7;
    src = (tk < 4) ? Wgrt : Wrel;
    k0 = (tk & 3) * 64; ncol0 = tn * 64;
    dst = WsmT; ldd = 512; nrow0 = tn * 64;
    k0 = k0; // dest k offset is tk*64 (incl. matrix split), source row is k0
    // dest col index = tk*64 + kk
    // handled below via kdst0
  }
  int kdst0 = (tb < 256) ? k0 : (((tb - 256) & 7) * 64);
  int c = threadIdx.x & 63, rb = threadIdx.x >> 6;
#pragma unroll
  for (int it = 0; it < 16; ++it) {
    int r = rb + it * 4;
    tile[r * 65 + c] = src[(size_t)(k0 + r) * 256 + ncol0 + c];
  }
  __syncthreads();
  int kk = threadIdx.x & 63;
#pragma unroll
  for (int it = 0; it < 16; ++it) {
    int nn = rb + it * 4;
    dst[(size_t)(nrow0 + nn) * ldd + kdst0 + kk] = f2bf(tile[kk * 65 + nn]);
  }
}

// ---- bf16 GEMM: C[M x Nt] = A[M x K] * BT[Nt x K]^T, 128x128 tile, BK=64.
// XCD-aware swizzle: xcd = b&7 owns m-tiles [xcd*32, xcd*32+32); its NT n-tiles for one
// m-tile are consecutive (stride-8) in dispatch order -> A panel L2-resident per XCD.
// EPI=0: store bf16 to Y (ldc=1024). EPI=1: z = acc + brel + bskip + Yskip, fp32 (ldc=256).
template <int EPI, int NT, int L2NT>
__global__ __launch_bounds__(256)
void diagcn_gemm(const unsigned short* __restrict__ A, const unsigned short* __restrict__ BT,
                 void* __restrict__ Cout, const unsigned short* __restrict__ Yfull,
                 const float* __restrict__ brel, const float* __restrict__ bskip, int K) {
  __shared__ unsigned short As[128 * 64];
  __shared__ unsigned short Bs[128 * 64];
  const int tid = threadIdx.x;
  const int w = tid >> 6, lane = tid & 63;
  const int wm = w >> 1, wn = w & 1;
  const int quad = lane >> 4, l15 = lane & 15;
  const int b = blockIdx.x;
  const int m0 = (((b & 7) << 5) + (b >> (3 + L2NT))) << 7;
  const int n0 = ((b >> 3) & (NT - 1)) << 7;
  const int rowg = lane >> 3;                 // 0..7 within 8-row group
  const int kbsw = (lane & 7) ^ rowg;         // XOR-swizzled source k-block

  f32x4 acc[4][4] = {};

  const unsigned short* Abase = A + (size_t)m0 * K + kbsw * 8;
  const unsigned short* Bbase = BT + (size_t)n0 * K + kbsw * 8;

  for (int k0 = 0; k0 < K; k0 += 64) {
#pragma unroll
    for (int t = 0; t < 4; ++t) {
      int grp = w * 4 + t;                    // 16 groups of 8 rows
      int rl = grp * 8 + rowg;
      ld_lds16(Abase + (size_t)rl * K + k0, &As[grp * 512]);
      ld_lds16(Bbase + (size_t)rl * K + k0, &Bs[grp * 512]);
    }
    __syncthreads();
#pragma unroll
    for (int ks = 0; ks < 2; ++ks) {
      bf16x8 av[4], bv[4];
      int kb = ks * 4 + quad;
#pragma unroll
      for (int i = 0; i < 4; ++i) {
        int ra = wm * 64 + i * 16 + l15;
        int rb = wn * 64 + i * 16 + l15;
        av[i] = *(const bf16x8*)&As[ra * 64 + ((kb ^ (ra & 7)) << 3)];
        bv[i] = *(const bf16x8*)&Bs[rb * 64 + ((kb ^ (rb & 7)) << 3)];
      }
#pragma unroll
      for (int i = 0; i < 4; ++i)
#pragma unroll
        for (int j = 0; j < 4; ++j)
          acc[i][j] = __builtin_amdgcn_mfma_f32_16x16x32_bf16(av[i], bv[j], acc[i][j], 0, 0, 0);
    }
    __syncthreads();
  }

  if (EPI == 0) {
    unsigned short* Y = (unsigned short*)Cout;
#pragma unroll
    for (int i = 0; i < 4; ++i)
#pragma unroll
      for (int j = 0; j < 4; ++j) {
        int row = m0 + wm * 64 + i * 16 + quad * 4;
        int col = n0 + wn * 64 + j * 16 + l15;
#pragma unroll
        for (int r = 0; r < 4; ++r)
          Y[(size_t)(row + r) * 1024 + col] = f2bf(acc[i][j][r]);
      }
  } else {
    float* Z = (float*)Cout;
#pragma unroll
    for (int i = 0; i < 4; ++i)
#pragma unroll
      for (int j = 0; j < 4; ++j) {
        int row = m0 + wm * 64 + i * 16 + quad * 4;
        int col = n0 + wn * 64 + j * 16 + l15;
#pragma unroll
        for (int r = 0; r < 4; ++r) {
          float v = acc[i][j][r] + brel[col] + bskip[col] +
                    bf2f(Yfull[(size_t)(row + r) * 1024 + 768 + col]);
          Z[(size_t)(row + r) * 256 + col] = v;
        }
      }
  }
}

// ---- RGCN aggregate, one wave per node, branchless unrolled window.
// h_i = Yroot_i + b + sum_r mean_{j in win, rel=r} Y_r[j]; writes bf16 h to A2[:,0:256].
// XCD swizzle: xcd owns a contiguous 4096-node slab -> window reuse stays in-XCD.
__global__ __launch_bounds__(256)
void diagcn_h(const unsigned short* __restrict__ Y, const int* __restrict__ spk,
              const float* __restrict__ brgcn, unsigned short* __restrict__ A2) {
  int b = blockIdx.x;
  int node = ((b & 7) << 12) + ((b >> 3) << 2) + (threadIdx.x >> 6);
  int lane = threadIdx.x & 63, c0 = lane << 2;
  int p = node & 255, dbase = node - p;
  int si = spk[node];
  float a0[4] = {0, 0, 0, 0}, a1[4] = {0, 0, 0, 0};
  float n0 = 0.f, n1 = 0.f;
#pragma unroll
  for (int d = -4; d <= 4; ++d) {
    int pj = p + d;
    float w = (pj >= 0 && pj < 256) ? 1.f : 0.f;
    int jc = pj < 0 ? 0 : (pj > 255 ? 255 : pj);
    int nj = dbase + jc;
    int rel = si & spk[nj];
    ushort4 v = *(const ushort4*)&Y[(size_t)nj * 1024 + (rel << 8) + c0];
    float w1 = rel ? w : 0.f, w0 = rel ? 0.f : w;
    a0[0] += bf2f(v.x) * w0; a1[0] += bf2f(v.x) * w1;
    a0[1] += bf2f(v.y) * w0; a1[1] += bf2f(v.y) * w1;
    a0[2] += bf2f(v.z) * w0; a1[2] += bf2f(v.z) * w1;
    a0[3] += bf2f(v.w) * w0; a1[3] += bf2f(v.w) * w1;
    n0 += w0; n1 += w1;
  }
  ushort4 vr = *(const ushort4*)&Y[(size_t)node * 1024 + 512 + c0];
  float4 bb = *(const float4*)&brgcn[c0];
  float i0 = 1.f / fmaxf(n0, 1.f), i1 = 1.f / fmaxf(n1, 1.f);
  ushort4 u;
  u.x = f2bf(bf2f(vr.x) + bb.x + a0[0] * i0 + a1[0] * i1);
  u.y = f2bf(bf2f(vr.y) + bb.y + a0[1] * i0 + a1[1] * i1);
  u.z = f2bf(bf2f(vr.z) + bb.z + a0[2] * i0 + a1[2] * i1);
  u.w = f2bf(bf2f(vr.w) + bb.w + a0[3] * i0 + a1[3] * i1);
  *(ushort4*)&A2[(size_t)node * 512 + c0] = u;
}

// ---- GraphConv neighbor sum (aggr=add over window incl. self), one wave per node.
__global__ __launch_bounds__(256)
void diagcn_neigh(unsigned short* __restrict__ A2) {
  int b = blockIdx.x;
  int node = ((b & 7) << 12) + ((b >> 3) << 2) + (threadIdx.x >> 6);
  int lane = threadIdx.x & 63, c0 = lane << 2;
  int p = node & 255, dbase = node - p;
  float s[4] = {0, 0, 0, 0};
#pragma unroll
  for (int d = -4; d <= 4; ++d) {
    int pj = p + d;
    float w = (pj >= 0 && pj < 256) ? 1.f : 0.f;
    int jc = pj < 0 ? 0 : (pj > 255 ? 255 : pj);
    ushort4 v = *(const ushort4*)&A2[(size_t)(dbase + jc) * 512 + c0];
    s[0] += bf2f(v.x) * w; s[1] += bf2f(v.y) * w;
    s[2] += bf2f(v.z) * w; s[3] += bf2f(v.w) * w;
  }
  ushort4 u; u.x = f2bf(s[0]); u.y = f2bf(s[1]); u.z = f2bf(s[2]); u.w = f2bf(s[3]);
  *(ushort4*)&A2[(size_t)node * 512 + 256 + c0] = u;
}

// ---- classifier + per-node loss: one wave per node
__global__ __launch_bounds__(256)
void diagcn_out(const float* __restrict__ z, const float* __restrict__ Wcls,
                const float* __restrict__ bcls, const int* __restrict__ labels,
                float* __restrict__ out, float* __restrict__ lossp) {
  __shared__ float Wc[256 * 7 + 7];
  for (int i = threadIdx.x; i < 256 * 7 + 7; i += 256)
    Wc[i] = (i < 1792) ? Wcls[i] : bcls[i - 1792];
  __syncthreads();
  int node = blockIdx.x * 4 + (threadIdx.x >> 6);
  int lane = threadIdx.x & 63;
  int c0 = lane << 2;
  float4 zv = *(const float4*)&z[(size_t)node * 256 + c0];
  float zz[4] = {zv.x, zv.y, zv.z, zv.w};
  float pr[7] = {0, 0, 0, 0, 0, 0, 0};
#pragma unroll
  for (int cc = 0; cc < 4; ++cc) {
    const float* wr = &Wc[(c0 + cc) * 7];
#pragma unroll
    for (int k = 0; k < 7; ++k) pr[k] += zz[cc] * wr[k];
  }
#pragma unroll
  for (int o = 32; o > 0; o >>= 1)
#pragma unroll
    for (int k = 0; k < 7; ++k) pr[k] += __shfl_down(pr[k], o, 64);
  if (lane == 0) {
    float o7[7], m = -1e30f;
#pragma unroll
    for (int k = 0; k < 7; ++k) {
      o7[k] = pr[k] + Wc[1792 + k];
      out[(size_t)node * 7 + k] = o7[k];
      m = fmaxf(m, o7[k]);
    }
    float s = 0;
#pragma unroll
    for (int k = 0; k < 7; ++k) s += expf(o7[k] - m);
    int lab = labels[node];
    lossp[node] = m + logf(s) - o7[lab];
  }
}

__global__ void diagcn_lred(const float* __restrict__ lp, float* __restrict__ dst) {
  __shared__ float sm[256];
  float s = 0;
  for (int i = threadIdx.x; i < NN; i += 256) s += lp[i];
  sm[threadIdx.x] = s;
  __syncthreads();
  for (int o = 128; o > 0; o >>= 1) {
    if (threadIdx.x < o) sm[threadIdx.x] += sm[threadIdx.x + o];
    __syncthreads();
  }
  if (threadIdx.x == 0) dst[0] = sm[0] * (1.0f / (float)NN);
}

extern "C" void kernel_launch(void* const* d_in, const int* in_sizes, int n_in,
                              void* d_out, int out_size, void* d_ws, size_t ws_size,
                              hipStream_t stream) {
  const float* x      = (const float*)d_in[0];
  const int* speakers = (const int*)d_in[2];
  const int* labels   = (const int*)d_in[3];
  const float* Wrgcn  = (const float*)d_in[6];
  const float* Wroot  = (const float*)d_in[7];
  const float* brgcn  = (const float*)d_in[8];
  const float* Wrel   = (const float*)d_in[9];
  const float* brel   = (const float*)d_in[10];
  const float* Wgrt   = (const float*)d_in[11];
  const float* Wskip  = (const float*)d_in[12];
  const float* bskip  = (const float*)d_in[13];
  const float* Wcls   = (const float*)d_in[14];
  const float* bcls   = (const float*)d_in[15];
  float* out = (float*)d_out;

  // workspace layout (bytes)
  const size_t OFF_XBF  = 0;                  // 67,108,864  (bf16 X; later reused for z+lossp)
  const size_t OFF_WBIG = 67108864;           //  2,097,152
  const size_t OFF_WSM  = 69206016;           //    262,144
  const size_t OFF_Y    = 69468160;           // 67,108,864  (bf16 [Y0|Y1|Yroot|Yskip])
  const size_t OFF_A2   = 136577024;          // 33,554,432  (bf16 [h|neigh])
  const size_t NEED     = 170131456;
  if (ws_size < NEED) return;  // insufficient scratch — would need a redesign

  char* ws = (char*)d_ws;
  unsigned short* Xbf   = (unsigned short*)(ws + OFF_XBF);
  unsigned short* WbigT = (unsigned short*)(ws + OFF_WBIG);
  unsigned short* WsmT  = (unsigned short*)(ws + OFF_WSM);
  unsigned short* Y     = (unsigned short*)(ws + OFF_Y);
  unsigned short* A2    = (unsigned short*)(ws + OFF_A2);
  float* z              = (float*)(ws + OFF_XBF);               // reuse (Xbf dead after GEMM1)
  float* lossp          = (float*)(ws + OFF_XBF + 33554432);

  diagcn_prep<<<dim3(32768 + 288), dim3(256), 0, stream>>>(x, Wrgcn, Wroot, Wskip, Wgrt, Wrel,
                                                           Xbf, WbigT, WsmT);
  // GEMM1: Y[32768 x 1024] = Xbf @ WbigT^T ; 2048 blocks, XCD-swizzled
  diagcn_gemm<0, 8, 3><<<dim3(2048), dim3(256), 0, stream>>>(Xbf, WbigT, (void*)Y,
                                                             nullptr, nullptr, nullptr, 1024);
  diagcn_h<<<dim3(NN / 4), dim3(256), 0, stream>>>(Y, speakers, brgcn, A2);
  diagcn_neigh<<<dim3(NN / 4), dim3(256), 0, stream>>>(A2);
  // GEMM2: z[32768 x 256] = A2 @ WsmT^T + brel + bskip + Yskip ; 512 blocks, swizzled
  diagcn_gemm<1, 2, 1><<<dim3(512), dim3(256), 0, stream>>>(A2, WsmT, (void*)z,
                                                            Y, brel, bskip, 512);
  diagcn_out<<<dim3(NN / 4), dim3(256), 0, stream>>>(z, Wcls, bcls, labels, out, lossp);
  diagcn_lred<<<dim3(1), dim3(256), 0, stream>>>(lossp, out + (size_t)NN * 7);
}

// Round 4
// 381.181 us; speedup vs baseline: 1.2126x; 1.0628x over previous
//
#include <hip/hip_runtime.h>

// Problem constants (fixed by reference): B=128, L=256, F=P=4, IN=1024, H=256, C=7
#define NN 32768        // N = B*L
#define INF 1024
#define HF 256

typedef __bf16 bf16x8 __attribute__((ext_vector_type(8)));
typedef float f32x4 __attribute__((ext_vector_type(4)));
typedef unsigned short u16x8 __attribute__((ext_vector_type(8)));

__device__ __forceinline__ float bf2f(unsigned short u) {
  union { unsigned int i; float f; } v; v.i = ((unsigned int)u) << 16; return v.f;
}
__device__ __forceinline__ unsigned short f2bf(float f) {
  union { float f; unsigned int i; } v; v.f = f;
  unsigned int x = v.i;
  return (unsigned short)((x + 0x7fffu + ((x >> 16) & 1u)) >> 16);  // RNE
}

// async global->LDS, 16B per lane; dest = lds base (wave-uniform) + lane*16
__device__ __forceinline__ void ld_lds16(const unsigned short* g, unsigned short* l) {
  __builtin_amdgcn_global_load_lds(
      (__attribute__((address_space(1))) const unsigned int*)g,
      (__attribute__((address_space(3))) unsigned int*)l, 16, 0, 0);
}

// ---- prep:
//  blocks [0,32768):        x fp32 -> bf16 (coalesced float4 copy)  (+loss zero in bid 0)
//  blocks [32768,32768+288): weight repack via 64x64 LDS transpose (coalesced both sides)
// WbigT[n][k] (1024x1024) = [W0|W1|Wroot|Wskip]^T ; WsmT[n][k] (256x512) = [Wgrt;Wrel]^T
__global__ __launch_bounds__(256)
void diagcn_prep(const float* __restrict__ x, const float* __restrict__ Wrgcn,
                 const float* __restrict__ Wroot, const float* __restrict__ Wskip,
                 const float* __restrict__ Wgrt, const float* __restrict__ Wrel,
                 unsigned short* __restrict__ Xbf, unsigned short* __restrict__ WbigT,
                 unsigned short* __restrict__ WsmT, float* __restrict__ loss) {
  int bid = blockIdx.x;
  if (bid < 32768) {
    if (bid == 0 && threadIdx.x == 0) loss[0] = 0.f;
    int idx = bid * 256 + threadIdx.x;   // float4 index into x
    float4 v = ((const float4*)x)[idx];
    ushort4 u; u.x = f2bf(v.x); u.y = f2bf(v.y); u.z = f2bf(v.z); u.w = f2bf(v.w);
    ((ushort4*)Xbf)[idx] = u;
    return;
  }
  __shared__ float tile[64 * 65];
  int tb = bid - 32768;
  const float* src;
  int k0, ncol0;
  unsigned short* dst;
  int ldd, nrow0;
  if (tb < 256) {            // WbigT tiles: tn 0..15, tk 0..15
    int tn = tb >> 4, tk = tb & 15;
    int mat = tn >> 2;
    src = (mat == 0) ? Wrgcn : (mat == 1) ? (Wrgcn + 262144) : (mat == 2) ? Wroot : Wskip;
    k0 = tk * 64; ncol0 = (tn & 3) * 64;
    dst = WbigT; ldd = 1024; nrow0 = tn * 64;
  } else {                   // WsmT tiles: tn 0..3, tk 0..7
    int t2 = tb - 256;
    int tn = t2 >> 3, tk = t2 & 7;
    src = (tk < 4) ? Wgrt : Wrel;
    k0 = (tk & 3) * 64; ncol0 = tn * 64;
    dst = WsmT; ldd = 512; nrow0 = tn * 64;
  }
  int kdst0 = (tb < 256) ? k0 : (((tb - 256) & 7) * 64);
  int c = threadIdx.x & 63, rb = threadIdx.x >> 6;
#pragma unroll
  for (int it = 0; it < 16; ++it) {
    int r = rb + it * 4;
    tile[r * 65 + c] = src[(size_t)(k0 + r) * 256 + ncol0 + c];
  }
  __syncthreads();
  int kk = threadIdx.x & 63;
#pragma unroll
  for (int it = 0; it < 16; ++it) {
    int nn = rb + it * 4;
    dst[(size_t)(nrow0 + nn) * ldd + kdst0 + kk] = f2bf(tile[kk * 65 + nn]);
  }
}

// ---- GEMM1: Y[32768 x 1024] = Xbf @ WbigT^T, 128x128 tile, BK=64, bf16 out.
// XCD-aware swizzle: xcd = b&7 owns m-tiles [xcd*32, xcd*32+32); its 8 n-tiles are
// consecutive in dispatch order -> A panel stays L2-resident per XCD.
__global__ __launch_bounds__(256)
void diagcn_gemm1(const unsigned short* __restrict__ A, const unsigned short* __restrict__ BT,
                  unsigned short* __restrict__ Y) {
  const int K = 1024;
  __shared__ unsigned short As[128 * 64];
  __shared__ unsigned short Bs[128 * 64];
  const int tid = threadIdx.x;
  const int w = tid >> 6, lane = tid & 63;
  const int wm = w >> 1, wn = w & 1;
  const int quad = lane >> 4, l15 = lane & 15;
  const int b = blockIdx.x;
  const int m0 = (((b & 7) << 5) + (b >> 6)) << 7;
  const int n0 = ((b >> 3) & 7) << 7;
  const int rowg = lane >> 3;
  const int kbsw = (lane & 7) ^ rowg;

  f32x4 acc[4][4] = {};
  const unsigned short* Abase = A + (size_t)m0 * K + kbsw * 8;
  const unsigned short* Bbase = BT + (size_t)n0 * K + kbsw * 8;

  for (int k0 = 0; k0 < K; k0 += 64) {
#pragma unroll
    for (int t = 0; t < 4; ++t) {
      int grp = w * 4 + t;
      int rl = grp * 8 + rowg;
      ld_lds16(Abase + (size_t)rl * K + k0, &As[grp * 512]);
      ld_lds16(Bbase + (size_t)rl * K + k0, &Bs[grp * 512]);
    }
    __syncthreads();
#pragma unroll
    for (int ks = 0; ks < 2; ++ks) {
      bf16x8 av[4], bv[4];
      int kb = ks * 4 + quad;
#pragma unroll
      for (int i = 0; i < 4; ++i) {
        int ra = wm * 64 + i * 16 + l15;
        int rb2 = wn * 64 + i * 16 + l15;
        av[i] = *(const bf16x8*)&As[ra * 64 + ((kb ^ (ra & 7)) << 3)];
        bv[i] = *(const bf16x8*)&Bs[rb2 * 64 + ((kb ^ (rb2 & 7)) << 3)];
      }
#pragma unroll
      for (int i = 0; i < 4; ++i)
#pragma unroll
        for (int j = 0; j < 4; ++j)
          acc[i][j] = __builtin_amdgcn_mfma_f32_16x16x32_bf16(av[i], bv[j], acc[i][j], 0, 0, 0);
    }
    __syncthreads();
  }
#pragma unroll
  for (int i = 0; i < 4; ++i)
#pragma unroll
    for (int j = 0; j < 4; ++j) {
      int row = m0 + wm * 64 + i * 16 + quad * 4;
      int col = n0 + wn * 64 + j * 16 + l15;
#pragma unroll
      for (int r = 0; r < 4; ++r)
        Y[(size_t)(row + r) * 1024 + col] = f2bf(acc[i][j][r]);
    }
}

// ---- RGCN aggregate, 2 nodes per wave (8 ch/lane, 16B loads), branchless window.
// h_i = Yroot_i + b + sum_r mean_{j in win, rel=r} Y_r[j]; bf16 h -> A2[:,0:256].
__global__ __launch_bounds__(256)
void diagcn_h(const unsigned short* __restrict__ Y, const int* __restrict__ spk,
              const float* __restrict__ brgcn, unsigned short* __restrict__ A2) {
  int b = blockIdx.x;
  int wv = threadIdx.x >> 6, lane = threadIdx.x & 63;
  int half = lane >> 5, li = lane & 31, c0 = li << 3;
  int node = ((b & 7) << 12) + ((b >> 3) << 3) + wv * 2 + half;
  int p = node & 255, dbase = node - p;
  int si = spk[node];
  float a0[8] = {}, a1[8] = {};
  float n0 = 0.f, n1 = 0.f;
#pragma unroll
  for (int d = -4; d <= 4; ++d) {
    int pj = p + d;
    float w = (pj >= 0 && pj < 256) ? 1.f : 0.f;
    int jc = pj < 0 ? 0 : (pj > 255 ? 255 : pj);
    int nj = dbase + jc;
    int rel = si & spk[nj];
    u16x8 v = *(const u16x8*)&Y[(size_t)nj * 1024 + (rel << 8) + c0];
    float w1 = rel ? w : 0.f, w0 = rel ? 0.f : w;
#pragma unroll
    for (int k = 0; k < 8; ++k) {
      float f = bf2f(v[k]);
      a0[k] += f * w0; a1[k] += f * w1;
    }
    n0 += w0; n1 += w1;
  }
  u16x8 vr = *(const u16x8*)&Y[(size_t)node * 1024 + 512 + c0];
  float i0 = 1.f / fmaxf(n0, 1.f), i1 = 1.f / fmaxf(n1, 1.f);
  u16x8 u;
#pragma unroll
  for (int k = 0; k < 8; ++k)
    u[k] = f2bf(bf2f(vr[k]) + brgcn[c0 + k] + a0[k] * i0 + a1[k] * i1);
  *(u16x8*)&A2[(size_t)node * 512 + c0] = u;
}

// ---- GraphConv neighbor sum (aggr=add over window incl. self), 2 nodes/wave.
__global__ __launch_bounds__(256)
void diagcn_neigh(unsigned short* __restrict__ A2) {
  int b = blockIdx.x;
  int wv = threadIdx.x >> 6, lane = threadIdx.x & 63;
  int half = lane >> 5, li = lane & 31, c0 = li << 3;
  int node = ((b & 7) << 12) + ((b >> 3) << 3) + wv * 2 + half;
  int p = node & 255, dbase = node - p;
  float s[8] = {};
#pragma unroll
  for (int d = -4; d <= 4; ++d) {
    int pj = p + d;
    float w = (pj >= 0 && pj < 256) ? 1.f : 0.f;
    int jc = pj < 0 ? 0 : (pj > 255 ? 255 : pj);
    u16x8 v = *(const u16x8*)&A2[(size_t)(dbase + jc) * 512 + c0];
#pragma unroll
    for (int k = 0; k < 8; ++k) s[k] += bf2f(v[k]) * w;
  }
  u16x8 u;
#pragma unroll
  for (int k = 0; k < 8; ++k) u[k] = f2bf(s[k]);
  *(u16x8*)&A2[(size_t)node * 512 + 256 + c0] = u;
}

// ---- GEMM2 + fused epilogue. 64x256 tile (full H per block), K=512.
// z = A2 @ WsmT^T + brel + bskip + Yskip; then out = z @ Wcls + bcls, log-softmax,
// per-row CE loss atomically accumulated. z never touches HBM.
__global__ __launch_bounds__(256)
void diagcn_gemm2(const unsigned short* __restrict__ A, const unsigned short* __restrict__ BT,
                  const unsigned short* __restrict__ Y, const float* __restrict__ Wcls,
                  const float* __restrict__ bcls, const float* __restrict__ brel,
                  const float* __restrict__ bskip, const int* __restrict__ labels,
                  float* __restrict__ out, float* __restrict__ loss) {
  const int K = 512;
  __shared__ unsigned short As[64 * 64];
  __shared__ unsigned short Bs[256 * 64];
  __shared__ float Wc[2312];   // [0,1792) Wcls | [1792,1799) bcls | [1800,2056) brel | [2056,2312) bskip
  for (int i = threadIdx.x; i < 2312; i += 256) {
    float v;
    if (i < 1792) v = Wcls[i];
    else if (i < 1799) v = bcls[i - 1792];
    else if (i < 1800) v = 0.f;
    else if (i < 2056) v = brel[i - 1800];
    else v = bskip[i - 2056];
    Wc[i] = v;
  }
  const int tid = threadIdx.x;
  const int w = tid >> 6, lane = tid & 63;
  const int quad = lane >> 4, l15 = lane & 15;
  const int b = blockIdx.x;
  const int m0 = (((b & 7) << 6) + (b >> 3)) << 6;   // 512 m-tiles of 64 rows
  const int rowg = lane >> 3;
  const int kbsw = (lane & 7) ^ rowg;

  f32x4 acc[16] = {};
  const unsigned short* Abase = A + (size_t)m0 * K + kbsw * 8;
  const unsigned short* Bbase = BT + kbsw * 8;

  for (int k0 = 0; k0 < K; k0 += 64) {
#pragma unroll
    for (int t = 0; t < 2; ++t) {      // A: 8 groups of 8 rows
      int grp = w * 2 + t;
      ld_lds16(Abase + (size_t)(grp * 8 + rowg) * K + k0, &As[grp * 512]);
    }
#pragma unroll
    for (int t = 0; t < 8; ++t) {      // B: 32 groups of 8 rows
      int grp = w * 8 + t;
      ld_lds16(Bbase + (size_t)(grp * 8 + rowg) * K + k0, &Bs[grp * 512]);
    }
    __syncthreads();
#pragma unroll
    for (int ks = 0; ks < 2; ++ks) {
      int kb = ks * 4 + quad;
      int ra = w * 16 + l15;
      bf16x8 av = *(const bf16x8*)&As[ra * 64 + ((kb ^ (ra & 7)) << 3)];
#pragma unroll
      for (int j = 0; j < 16; ++j) {
        int rb2 = j * 16 + l15;
        bf16x8 bv = *(const bf16x8*)&Bs[rb2 * 64 + ((kb ^ (rb2 & 7)) << 3)];
        acc[j] = __builtin_amdgcn_mfma_f32_16x16x32_bf16(av, bv, acc[j], 0, 0, 0);
      }
    }
    __syncthreads();
  }

  // ---- epilogue: bias + skip, classifier partials
  float wsum[4][7] = {};
#pragma unroll
  for (int j = 0; j < 16; ++j) {
    int col = j * 16 + l15;
    float bb = Wc[1800 + col] + Wc[2056 + col];
#pragma unroll
    for (int r = 0; r < 4; ++r) {
      int row = m0 + w * 16 + quad * 4 + r;
      float z = acc[j][r] + bb + bf2f(Y[(size_t)row * 1024 + 768 + col]);
#pragma unroll
      for (int c = 0; c < 7; ++c) wsum[r][c] += z * Wc[col * 7 + c];
    }
  }
  // reduce over the 16 lanes of each quad (cols) -> every lane holds full row dots
#pragma unroll
  for (int o = 1; o < 16; o <<= 1)
#pragma unroll
    for (int r = 0; r < 4; ++r)
#pragma unroll
      for (int c = 0; c < 7; ++c) wsum[r][c] += __shfl_xor(wsum[r][c], o, 64);

  float lsum = 0.f;
#pragma unroll
  for (int r = 0; r < 4; ++r) {
    int row = m0 + w * 16 + quad * 4 + r;
    float o7[7], mx = -1e30f;
#pragma unroll
    for (int c = 0; c < 7; ++c) {
      o7[c] = wsum[r][c] + Wc[1792 + c];
      mx = fmaxf(mx, o7[c]);
    }
    if (l15 < 7) out[(size_t)row * 7 + l15] = o7[l15];
    float s = 0.f;
#pragma unroll
    for (int c = 0; c < 7; ++c) s += expf(o7[c] - mx);
    int lab = labels[row];
    lsum += mx + logf(s) - o7[lab];
  }
  // quad-totals are lane-identical; combine the 4 quads
  lsum += __shfl_xor(lsum, 16, 64);
  lsum += __shfl_xor(lsum, 32, 64);
  if (lane == 0) atomicAdd(loss, lsum * (1.0f / (float)NN));
}

extern "C" void kernel_launch(void* const* d_in, const int* in_sizes, int n_in,
                              void* d_out, int out_size, void* d_ws, size_t ws_size,
                              hipStream_t stream) {
  const float* x      = (const float*)d_in[0];
  const int* speakers = (const int*)d_in[2];
  const int* labels   = (const int*)d_in[3];
  const float* Wrgcn  = (const float*)d_in[6];
  const float* Wroot  = (const float*)d_in[7];
  const float* brgcn  = (const float*)d_in[8];
  const float* Wrel   = (const float*)d_in[9];
  const float* brel   = (const float*)d_in[10];
  const float* Wgrt   = (const float*)d_in[11];
  const float* Wskip  = (const float*)d_in[12];
  const float* bskip  = (const float*)d_in[13];
  const float* Wcls   = (const float*)d_in[14];
  const float* bcls   = (const float*)d_in[15];
  float* out = (float*)d_out;
  float* loss = out + (size_t)NN * 7;

  // workspace layout (bytes)
  const size_t OFF_XBF  = 0;                  // 67,108,864  (bf16 X)
  const size_t OFF_WBIG = 67108864;           //  2,097,152
  const size_t OFF_WSM  = 69206016;           //    262,144
  const size_t OFF_Y    = 69468160;           // 67,108,864  (bf16 [Y0|Y1|Yroot|Yskip])
  const size_t OFF_A2   = 136577024;          // 33,554,432  (bf16 [h|neigh])
  const size_t NEED     = 170131456;
  if (ws_size < NEED) return;

  char* ws = (char*)d_ws;
  unsigned short* Xbf   = (unsigned short*)(ws + OFF_XBF);
  unsigned short* WbigT = (unsigned short*)(ws + OFF_WBIG);
  unsigned short* WsmT  = (unsigned short*)(ws + OFF_WSM);
  unsigned short* Y     = (unsigned short*)(ws + OFF_Y);
  unsigned short* A2    = (unsigned short*)(ws + OFF_A2);

  diagcn_prep<<<dim3(33056), dim3(256), 0, stream>>>(x, Wrgcn, Wroot, Wskip, Wgrt, Wrel,
                                                     Xbf, WbigT, WsmT, loss);
  diagcn_gemm1<<<dim3(2048), dim3(256), 0, stream>>>(Xbf, WbigT, Y);
  diagcn_h<<<dim3(NN / 8), dim3(256), 0, stream>>>(Y, speakers, brgcn, A2);
  diagcn_neigh<<<dim3(NN / 8), dim3(256), 0, stream>>>(A2);
  diagcn_gemm2<<<dim3(512), dim3(256), 0, stream>>>(A2, WsmT, Y, Wcls, bcls, brel, bskip,
                                                    labels, out, loss);
}